// Round 2
// baseline (1881.265 us; speedup 1.0000x reference)
//
#include <hip/hip_runtime.h>

typedef __bf16 bf16;
typedef __attribute__((ext_vector_type(4))) float floatx4;
typedef __attribute__((ext_vector_type(8))) bf16 bf16x8;
typedef __attribute__((ext_vector_type(4))) bf16 bf16x4;

typedef const __attribute__((address_space(1))) void gconst_t;
typedef __attribute__((address_space(3))) void lds_t;

__device__ __forceinline__ void load_lds16(const void* g, void* l) {
  __builtin_amdgcn_global_load_lds((gconst_t*)g, (lds_t*)l, 16, 0, 0);
}

__device__ __forceinline__ float sigm(float x) { return 1.f / (1.f + __expf(-x)); }
__device__ __forceinline__ float tanh_f(float x) { return 2.f / (1.f + __expf(-2.f * x)) - 1.f; }

// ---------------------------------------------------------------------------
// fp32 -> bf16 convert (vectorized x4)
// ---------------------------------------------------------------------------
__global__ void k_cvt(const float* __restrict__ in, bf16* __restrict__ out, int n4) {
  int i = blockIdx.x * 256 + threadIdx.x;
  if (i < n4) {
    float4 v = ((const float4*)in)[i];
    bf16x4 u = { (bf16)v.x, (bf16)v.y, (bf16)v.z, (bf16)v.w };
    ((bf16x4*)out)[i] = u;
  }
}

__global__ void k_bias_sum(const float* __restrict__ a, const float* __restrict__ b,
                           float* __restrict__ o, int n) {
  int i = blockIdx.x * 256 + threadIdx.x;
  if (i < n) o[i] = a[i] + b[i];
}

__global__ void k_zero(unsigned* __restrict__ p) {
  if (threadIdx.x == 0 && blockIdx.x == 0) p[0] = 0u;
}

// ---------------------------------------------------------------------------
// linear (32x2048 @ 2048x512^T) + batchnorm over batch dim -> xs row t=0 (bf16)
// ---------------------------------------------------------------------------
__global__ __launch_bounds__(256) void k_linbn(
    const float* __restrict__ img, const float* __restrict__ W,
    const float* __restrict__ lb, const float* __restrict__ gamma,
    const float* __restrict__ beta, bf16* __restrict__ xs)
{
  const int e = blockIdx.x;                 // 0..511
  const int wave = threadIdx.x >> 6, lane = threadIdx.x & 63;
  __shared__ float sums[32];
  const float* wrow = W + (size_t)e * 2048;
  for (int b = wave; b < 32; b += 4) {
    const float* irow = img + (size_t)b * 2048;
    float s = 0.f;
#pragma unroll
    for (int j = 0; j < 8; ++j) {
      const int k = j * 256 + lane * 4;
      float4 a = *(const float4*)(irow + k);
      float4 w = *(const float4*)(wrow + k);
      s += a.x * w.x + a.y * w.y + a.z * w.z + a.w * w.w;
    }
#pragma unroll
    for (int off = 32; off > 0; off >>= 1) s += __shfl_down(s, off);
    if (lane == 0) sums[b] = s + lb[e];
  }
  __syncthreads();
  if (threadIdx.x < 32) {
    const float x = sums[threadIdx.x];
    float m = x, m2 = x * x;
#pragma unroll
    for (int mask = 16; mask > 0; mask >>= 1) {
      m  += __shfl_xor(m, mask);
      m2 += __shfl_xor(m2, mask);
    }
    m *= (1.f / 32.f); m2 *= (1.f / 32.f);
    const float var = m2 - m * m;
    const float xn = gamma[e] * (x - m) * rsqrtf(var + 1e-5f) + beta[e];
    xs[(size_t)threadIdx.x * 64 * 512 + e] = (bf16)xn;  // row r = b*64 + 0
  }
}

// ---------------------------------------------------------------------------
// embedding gather -> xs rows t=1..63 (bf16)
// ---------------------------------------------------------------------------
__global__ void k_embed(const int* __restrict__ cap, const float* __restrict__ emb,
                        bf16* __restrict__ xs)
{
  const int blk = blockIdx.x;               // 0..2015
  const int b = blk / 63, j = blk % 63;     // t = j+1
  const int tok = cap[b * 64 + j];
  const float* src = emb + (size_t)tok * 512;
  bf16* dst = xs + ((size_t)b * 64 + j + 1) * 512;
  float4 v = ((const float4*)src)[threadIdx.x];
  bf16x4 u = { (bf16)v.x, (bf16)v.y, (bf16)v.z, (bf16)v.w };
  *(bf16x4*)(dst + threadIdx.x * 4) = u;
}

// ---------------------------------------------------------------------------
// GEMM: C[M,N] = A[M,K](bf16) @ Bt[N,K](fp32, cvt during staging)^T + bias.
// m97 structure: 128x128 tile, BK=32, 4 waves 2x2, 4x4 16x16x32 MFMA tiles.
// XCD-chunked block swizzle (nwg % 8 == 0, gridDim.x == 16 -> 16 row tiles):
// each XCD owns a contiguous logical chunk; the 16 row-tiles sharing a B
// panel are consecutive -> B panel fetched once per XCD, L2-resident.
// ---------------------------------------------------------------------------
__global__ __launch_bounds__(256) void k_gemm(
    const bf16* __restrict__ A, const float* __restrict__ Bt,
    const float* __restrict__ bias, float* __restrict__ C,
    int K, int N)
{
  __shared__ bf16 lA[128 * 32];
  __shared__ bf16 lB[128 * 32];
  const int tid = threadIdx.x;
  const int lane = tid & 63;
  const int wm = ((tid >> 6) >> 1) * 64;
  const int wn = ((tid >> 6) & 1) * 64;
  const int nwg = gridDim.x * gridDim.y;
  int wg = blockIdx.y * gridDim.x + blockIdx.x;
  wg = (wg & 7) * (nwg >> 3) + (wg >> 3);        // XCD-chunked, bijective (nwg%8==0)
  const size_t row0 = (size_t)(wg & 15) * 128;   // gridDim.x == 16 always
  const size_t col0 = (size_t)(wg >> 4) * 128;
  floatx4 acc[4][4] = {};
  const bf16*  aSrc = A  + (row0 + (tid >> 2)) * (size_t)K + (tid & 3) * 8;
  const float* bSrc = Bt + (col0 + (tid >> 3)) * (size_t)K + (tid & 7) * 4;
  char* lAb = (char*)&lA[0];

  for (int k0 = 0; k0 < K; k0 += 32) {
    __syncthreads();
#pragma unroll
    for (int s = 0; s < 2; ++s)   // A tile: 128x32 bf16 via lds-DMA, 2 shots
      load_lds16(aSrc + (size_t)s * 64 * K + k0, lAb + s * 4096 + tid * 16);
#pragma unroll
    for (int s = 0; s < 4; ++s) { // B tile: 128x32 fp32 -> bf16, 4 shots
      float4 v = *(const float4*)(bSrc + (size_t)s * 32 * K + k0);
      bf16x4 u = { (bf16)v.x, (bf16)v.y, (bf16)v.z, (bf16)v.w };
      *(bf16x4*)&lB[(s * 32 + (tid >> 3)) * 32 + (tid & 7) * 4] = u;
    }
    __syncthreads();
    bf16x8 af[4], bfv[4];
#pragma unroll
    for (int i = 0; i < 4; ++i)
      af[i] = *(const bf16x8*)&lA[(wm + i * 16 + (lane & 15)) * 32 + (lane >> 4) * 8];
#pragma unroll
    for (int j = 0; j < 4; ++j)
      bfv[j] = *(const bf16x8*)&lB[(wn + j * 16 + (lane & 15)) * 32 + (lane >> 4) * 8];
#pragma unroll
    for (int i = 0; i < 4; ++i)
#pragma unroll
      for (int j = 0; j < 4; ++j)
        acc[i][j] = __builtin_amdgcn_mfma_f32_16x16x32_bf16(af[i], bfv[j], acc[i][j], 0, 0, 0);
  }
#pragma unroll
  for (int i = 0; i < 4; ++i)
#pragma unroll
    for (int j = 0; j < 4; ++j)
#pragma unroll
      for (int r = 0; r < 4; ++r) {
        const size_t row = row0 + wm + i * 16 + (lane >> 4) * 4 + r;
        const size_t col = col0 + wn + j * 16 + (lane & 15);
        C[row * (size_t)N + col] = acc[i][j][r] + bias[col];
      }
}

// ---------------------------------------------------------------------------
// Persistent LSTM scan: one launch runs all 64 steps of one layer.
// 128 blocks x 256 threads (64 KiB LDS -> 2 blocks/CU possible, 128 << limit,
// all co-resident in practice). Block owns 8 hidden cols x 4 gates.
// Whh slice (32x1024 bf16 = 64 KB) staged in LDS ONCE, rows interleaved
// r = col_local*4 + gate and XOR-swizzled vs the stride-2048B bank conflict.
// We compute mfma(A=Whh_lds, B=h): C/D row = (lane>>4)*4 + r puts the 4 gate
// pre-activations of one (batch,col) pair into ONE lane's 4 acc regs ->
// gate math is lane-local; cell state lives in a VGPR.
// h exchanged through global + device-scope epoch barrier per step.
// Barrier has a bounded-spin escape hatch: a broken barrier produces a wrong
// answer (graceful bench fail), never a wedged GPU.
// ---------------------------------------------------------------------------
__device__ __forceinline__ void gbar(unsigned* bar) {
  __syncthreads();                        // all waves drain vmcnt: h stores in L2
  if (threadIdx.x == 0) {
    unsigned v = __hip_atomic_fetch_add(bar, 1u, __ATOMIC_RELEASE,
                                        __HIP_MEMORY_SCOPE_AGENT);  // wbl2
    const unsigned target = (v & ~127u) + 128u;     // NBLK = 128 participants
    int spins = 0;
    while (__hip_atomic_load(bar, __ATOMIC_RELAXED,
                             __HIP_MEMORY_SCOPE_AGENT) < target) {
      __builtin_amdgcn_s_sleep(8);
      if (++spins > 20000) break;         // ~4 ms escape: fail, don't hang
    }
    __builtin_amdgcn_fence(__ATOMIC_ACQUIRE, "agent");  // inv L1 + L2
  }
  __syncthreads();
}

__global__ __launch_bounds__(256) void k_lstm_scan(
    bf16* __restrict__ hs, const float* __restrict__ pre,
    const bf16* __restrict__ whh, unsigned* __restrict__ bar)
{
  __shared__ bf16 lW[32 * 1024];               // 64 KB exactly
  const int tid  = threadIdx.x;
  const int lane = tid & 63;
  const int wave = tid >> 6;
  const int tn   = wave >> 1;                  // col-tile: cols 0-3 / 4-7
  const int tb   = wave & 1;                   // batch-tile: b 0-15 / 16-31
  const int n0   = blockIdx.x * 8;             // this block's hidden cols

  // ---- stage Whh slice: LDS row r <-> global row (r&3)*1024 + n0 + (r>>2)
#pragma unroll
  for (int it = 0; it < 16; ++it) {
    const int idx  = it * 256 + tid;           // 16B-chunk id, 0..4095
    const int r    = idx >> 7;                 // lds row 0..31
    const int c16  = idx & 127;                // 16B chunk within row
    const int grow = (r & 3) * 1024 + n0 + (r >> 2);
    const bf16x8 v = *(const bf16x8*)(whh + (size_t)grow * 1024 + c16 * 8);
    int byte = r * 2048 + c16 * 16;
    byte ^= (r & 7) << 4;                      // bank-conflict swizzle
    *(bf16x8*)((char*)lW + byte) = v;
  }
  __syncthreads();

  const int arow  = tn * 16 + (lane & 15);     // Whh LDS row for A-frag
  const int axor  = (arow & 7) << 4;
  const int abase = arow * 2048 + (lane >> 4) * 16;
  const int brow  = tb * 16 + (lane & 15);     // batch row (B-frag & owner)
  const int cown  = tn * 4 + (lane >> 4);      // owned col within block
  const char* lWb = (const char*)lW;

  float cstate = 0.f;
  const float* preb = pre + (size_t)brow * 64 * 4096 + (n0 + cown);
  bf16* hw = hs + (size_t)brow * 64 * 1024 + (n0 + cown);
  const bf16* hr = hs + (size_t)brow * 65536 + (lane >> 4) * 8;

#pragma unroll 1
  for (int t = 0; t < 64; ++t) {
    // pre loads issued before the barrier (pre is static) -> latency hidden
    const float* pp = preb + (size_t)t * 4096;
    float g0 = pp[0], g1 = pp[1024], g2 = pp[2048], g3 = pp[3072];
    if (t > 0) {
      gbar(bar);                               // h_{t-1} now globally visible
      const bf16* hp = hr + (size_t)(t - 1) * 1024;
      floatx4 acc0 = {}, acc1 = {};
#pragma unroll
      for (int kk = 0; kk < 32; kk += 2) {
        const bf16x8 a0 = *(const bf16x8*)(lWb + ((abase + kk * 64) ^ axor));
        const bf16x8 b0 = *(const bf16x8*)(hp + kk * 32);
        acc0 = __builtin_amdgcn_mfma_f32_16x16x32_bf16(a0, b0, acc0, 0, 0, 0);
        const bf16x8 a1 = *(const bf16x8*)(lWb + ((abase + kk * 64 + 64) ^ axor));
        const bf16x8 b1 = *(const bf16x8*)(hp + kk * 32 + 32);
        acc1 = __builtin_amdgcn_mfma_f32_16x16x32_bf16(a1, b1, acc1, 0, 0, 0);
      }
      g0 += acc0[0] + acc1[0];
      g1 += acc0[1] + acc1[1];
      g2 += acc0[2] + acc1[2];
      g3 += acc0[3] + acc1[3];
    }
    const float iv = sigm(g0), fv = sigm(g1), gv = tanh_f(g2), ov = sigm(g3);
    cstate = fv * cstate + iv * gv;
    hw[(size_t)t * 1024] = (bf16)(ov * tanh_f(cstate));
  }
}

// ---------------------------------------------------------------------------
extern "C" void kernel_launch(void* const* d_in, const int* in_sizes, int n_in,
                              void* d_out, int out_size, void* d_ws, size_t ws_size,
                              hipStream_t stream)
{
  const float* image = (const float*)d_in[0];
  const int*   caps  = (const int*)d_in[1];
  const float* linW  = (const float*)d_in[2];
  const float* linb  = (const float*)d_in[3];
  const float* gamma = (const float*)d_in[4];
  const float* beta  = (const float*)d_in[5];
  const float* emb   = (const float*)d_in[6];
  const float* Wih0  = (const float*)d_in[7];
  const float* Whh0  = (const float*)d_in[8];
  const float* bih0  = (const float*)d_in[9];
  const float* bhh0  = (const float*)d_in[10];
  const float* Wih1  = (const float*)d_in[11];
  const float* Whh1  = (const float*)d_in[12];
  const float* bih1  = (const float*)d_in[13];
  const float* bhh1  = (const float*)d_in[14];
  const float* fcW   = (const float*)d_in[15];
  const float* fcb   = (const float*)d_in[16];
  float* out = (float*)d_out;

  char* ws = (char*)d_ws;
  size_t off = 0;
  auto alloc = [&](size_t bytes) {
    char* p = ws + off;
    off += (bytes + 255) & ~(size_t)255;
    return p;
  };
  // footprint kept at the previously-proven ~58 MB
  bf16*  whh0b = (bf16*)alloc(4096ull * 1024 * 2);
  bf16*  whh1b = (bf16*)alloc(4096ull * 1024 * 2);
  bf16*  xsb   = (bf16*)alloc(2048ull * 512 * 2);
  bf16*  hs0b  = (bf16*)alloc(2048ull * 1024 * 2);
  bf16*  hs1b  = (bf16*)alloc(2048ull * 1024 * 2);
  float* pre   = (float*)alloc(2048ull * 4096 * 4);
  float* bsum0 = (float*)alloc(4096 * 4);
  float* bsum1 = (float*)alloc(4096 * 4);
  unsigned* bar = (unsigned*)alloc(256);

  k_zero<<<1, 64, 0, stream>>>(bar);
  k_cvt<<<4096, 256, 0, stream>>>(Whh0, whh0b, 4096 * 1024 / 4);
  k_cvt<<<4096, 256, 0, stream>>>(Whh1, whh1b, 4096 * 1024 / 4);
  k_bias_sum<<<16, 256, 0, stream>>>(bih0, bhh0, bsum0, 4096);
  k_bias_sum<<<16, 256, 0, stream>>>(bih1, bhh1, bsum1, 4096);
  k_linbn<<<512, 256, 0, stream>>>(image, linW, linb, gamma, beta, xsb);
  k_embed<<<2016, 128, 0, stream>>>(caps, emb, xsb);

  // layer 0
  k_gemm<<<dim3(16, 32), 256, 0, stream>>>(xsb, Wih0, bsum0, pre, 512, 4096);
  k_lstm_scan<<<128, 256, 0, stream>>>(hs0b, pre, whh0b, bar);
  // layer 1
  k_gemm<<<dim3(16, 32), 256, 0, stream>>>(hs0b, Wih1, bsum1, pre, 1024, 4096);
  k_lstm_scan<<<128, 256, 0, stream>>>(hs1b, pre, whh1b, bar);
  // vocab projection
  k_gemm<<<dim3(16, 250), 256, 0, stream>>>(hs1b, fcW, fcb, out, 1024, 32000);

  (void)in_sizes; (void)n_in; (void)out_size; (void)ws_size;
}

// Round 3
// 1481.403 us; speedup vs baseline: 1.2699x; 1.2699x over previous
//
#include <hip/hip_runtime.h>

typedef __bf16 bf16;
typedef __attribute__((ext_vector_type(4))) float floatx4;
typedef __attribute__((ext_vector_type(8))) bf16 bf16x8;
typedef __attribute__((ext_vector_type(4))) bf16 bf16x4;

typedef const __attribute__((address_space(1))) void gconst_t;
typedef __attribute__((address_space(3))) void lds_t;

__device__ __forceinline__ void load_lds16(const void* g, void* l) {
  __builtin_amdgcn_global_load_lds((gconst_t*)g, (lds_t*)l, 16, 0, 0);
}

__device__ __forceinline__ float sigm(float x) { return 1.f / (1.f + __expf(-x)); }
__device__ __forceinline__ float tanh_f(float x) { return 2.f / (1.f + __expf(-2.f * x)) - 1.f; }

// --- device-coherent (cross-XCD) access helpers: bypass L1/L2 via sc0 sc1 ---
__device__ __forceinline__ void st_coh_u16(void* p, unsigned v) {
  asm volatile("global_store_short %0, %1, off sc0 sc1" :: "v"(p), "v"(v) : "memory");
}
__device__ __forceinline__ void st_coh_u32(void* p, unsigned v) {
  asm volatile("global_store_dword %0, %1, off sc0 sc1" :: "v"(p), "v"(v) : "memory");
}
__device__ __forceinline__ uint2 ld_coh_u32x2(const void* p) {
  uint2 r;
  asm volatile("global_load_dwordx2 %0, %1, off sc0 sc1\n\ts_waitcnt vmcnt(0)"
               : "=v"(r) : "v"(p) : "memory");
  return r;
}

// ---------------------------------------------------------------------------
// fp32 -> bf16 convert (vectorized x4)
// ---------------------------------------------------------------------------
__global__ void k_cvt(const float* __restrict__ in, bf16* __restrict__ out, int n4) {
  int i = blockIdx.x * 256 + threadIdx.x;
  if (i < n4) {
    float4 v = ((const float4*)in)[i];
    bf16x4 u = { (bf16)v.x, (bf16)v.y, (bf16)v.z, (bf16)v.w };
    ((bf16x4*)out)[i] = u;
  }
}

__global__ void k_bias_sum(const float* __restrict__ a, const float* __restrict__ b,
                           float* __restrict__ o, int n) {
  int i = blockIdx.x * 256 + threadIdx.x;
  if (i < n) o[i] = a[i] + b[i];
}

__global__ void k_zero(unsigned* __restrict__ p) {
  p[threadIdx.x] = 0u;   // 256 flag words (two 128-block layers)
}

// ---------------------------------------------------------------------------
// linear (32x2048 @ 2048x512^T) + batchnorm over batch dim -> xs row t=0 (bf16)
// ---------------------------------------------------------------------------
__global__ __launch_bounds__(256) void k_linbn(
    const float* __restrict__ img, const float* __restrict__ W,
    const float* __restrict__ lb, const float* __restrict__ gamma,
    const float* __restrict__ beta, bf16* __restrict__ xs)
{
  const int e = blockIdx.x;                 // 0..511
  const int wave = threadIdx.x >> 6, lane = threadIdx.x & 63;
  __shared__ float sums[32];
  const float* wrow = W + (size_t)e * 2048;
  for (int b = wave; b < 32; b += 4) {
    const float* irow = img + (size_t)b * 2048;
    float s = 0.f;
#pragma unroll
    for (int j = 0; j < 8; ++j) {
      const int k = j * 256 + lane * 4;
      float4 a = *(const float4*)(irow + k);
      float4 w = *(const float4*)(wrow + k);
      s += a.x * w.x + a.y * w.y + a.z * w.z + a.w * w.w;
    }
#pragma unroll
    for (int off = 32; off > 0; off >>= 1) s += __shfl_down(s, off);
    if (lane == 0) sums[b] = s + lb[e];
  }
  __syncthreads();
  if (threadIdx.x < 32) {
    const float x = sums[threadIdx.x];
    float m = x, m2 = x * x;
#pragma unroll
    for (int mask = 16; mask > 0; mask >>= 1) {
      m  += __shfl_xor(m, mask);
      m2 += __shfl_xor(m2, mask);
    }
    m *= (1.f / 32.f); m2 *= (1.f / 32.f);
    const float var = m2 - m * m;
    const float xn = gamma[e] * (x - m) * rsqrtf(var + 1e-5f) + beta[e];
    xs[(size_t)threadIdx.x * 64 * 512 + e] = (bf16)xn;  // row r = b*64 + 0
  }
}

// ---------------------------------------------------------------------------
// embedding gather -> xs rows t=1..63 (bf16)
// ---------------------------------------------------------------------------
__global__ void k_embed(const int* __restrict__ cap, const float* __restrict__ emb,
                        bf16* __restrict__ xs)
{
  const int blk = blockIdx.x;               // 0..2015
  const int b = blk / 63, j = blk % 63;     // t = j+1
  const int tok = cap[b * 64 + j];
  const float* src = emb + (size_t)tok * 512;
  bf16* dst = xs + ((size_t)b * 64 + j + 1) * 512;
  float4 v = ((const float4*)src)[threadIdx.x];
  bf16x4 u = { (bf16)v.x, (bf16)v.y, (bf16)v.z, (bf16)v.w };
  *(bf16x4*)(dst + threadIdx.x * 4) = u;
}

// ---------------------------------------------------------------------------
// GEMM: C[M,N] = A[M,K](bf16) @ Bt[N,K](fp32, cvt during staging)^T + bias.
// m97 structure + XCD-chunked swizzle. (fallback / small-GEMM path)
// ---------------------------------------------------------------------------
__global__ __launch_bounds__(256) void k_gemm(
    const bf16* __restrict__ A, const float* __restrict__ Bt,
    const float* __restrict__ bias, float* __restrict__ C,
    int K, int N)
{
  __shared__ bf16 lA[128 * 32];
  __shared__ bf16 lB[128 * 32];
  const int tid = threadIdx.x;
  const int lane = tid & 63;
  const int wm = ((tid >> 6) >> 1) * 64;
  const int wn = ((tid >> 6) & 1) * 64;
  const int nwg = gridDim.x * gridDim.y;
  int wg = blockIdx.y * gridDim.x + blockIdx.x;
  wg = (wg & 7) * (nwg >> 3) + (wg >> 3);        // XCD-chunked, bijective (nwg%8==0)
  const size_t row0 = (size_t)(wg & 15) * 128;   // gridDim.x == 16 always
  const size_t col0 = (size_t)(wg >> 4) * 128;
  floatx4 acc[4][4] = {};
  const bf16*  aSrc = A  + (row0 + (tid >> 2)) * (size_t)K + (tid & 3) * 8;
  const float* bSrc = Bt + (col0 + (tid >> 3)) * (size_t)K + (tid & 7) * 4;
  char* lAb = (char*)&lA[0];

  for (int k0 = 0; k0 < K; k0 += 32) {
    __syncthreads();
#pragma unroll
    for (int s = 0; s < 2; ++s)   // A tile: 128x32 bf16 via lds-DMA, 2 shots
      load_lds16(aSrc + (size_t)s * 64 * K + k0, lAb + s * 4096 + tid * 16);
#pragma unroll
    for (int s = 0; s < 4; ++s) { // B tile: 128x32 fp32 -> bf16, 4 shots
      float4 v = *(const float4*)(bSrc + (size_t)s * 32 * K + k0);
      bf16x4 u = { (bf16)v.x, (bf16)v.y, (bf16)v.z, (bf16)v.w };
      *(bf16x4*)&lB[(s * 32 + (tid >> 3)) * 32 + (tid & 7) * 4] = u;
    }
    __syncthreads();
    bf16x8 af[4], bfv[4];
#pragma unroll
    for (int i = 0; i < 4; ++i)
      af[i] = *(const bf16x8*)&lA[(wm + i * 16 + (lane & 15)) * 32 + (lane >> 4) * 8];
#pragma unroll
    for (int j = 0; j < 4; ++j)
      bfv[j] = *(const bf16x8*)&lB[(wn + j * 16 + (lane & 15)) * 32 + (lane >> 4) * 8];
#pragma unroll
    for (int i = 0; i < 4; ++i)
#pragma unroll
      for (int j = 0; j < 4; ++j)
        acc[i][j] = __builtin_amdgcn_mfma_f32_16x16x32_bf16(af[i], bfv[j], acc[i][j], 0, 0, 0);
  }
#pragma unroll
  for (int i = 0; i < 4; ++i)
#pragma unroll
    for (int j = 0; j < 4; ++j)
#pragma unroll
      for (int r = 0; r < 4; ++r) {
        const size_t row = row0 + wm + i * 16 + (lane >> 4) * 4 + r;
        const size_t col = col0 + wn + j * 16 + (lane & 15);
        C[row * (size_t)N + col] = acc[i][j][r] + bias[col];
      }
}

// ---------------------------------------------------------------------------
// GEMM variant: B already bf16 -> both operands via lds-DMA (m97 fast path).
// Identical numerics to k_gemm (B was rounded to bf16 during staging there).
// ---------------------------------------------------------------------------
__global__ __launch_bounds__(256) void k_gemm_bf(
    const bf16* __restrict__ A, const bf16* __restrict__ B,
    const float* __restrict__ bias, float* __restrict__ C,
    int K, int N)
{
  __shared__ bf16 lA[128 * 32];
  __shared__ bf16 lB[128 * 32];
  const int tid = threadIdx.x;
  const int lane = tid & 63;
  const int wm = ((tid >> 6) >> 1) * 64;
  const int wn = ((tid >> 6) & 1) * 64;
  const int nwg = gridDim.x * gridDim.y;
  int wg = blockIdx.y * gridDim.x + blockIdx.x;
  wg = (wg & 7) * (nwg >> 3) + (wg >> 3);
  const size_t row0 = (size_t)(wg & 15) * 128;
  const size_t col0 = (size_t)(wg >> 4) * 128;
  floatx4 acc[4][4] = {};
  const bf16* aSrc = A + (row0 + (tid >> 2)) * (size_t)K + (tid & 3) * 8;
  const bf16* bSrc = B + (col0 + (tid >> 2)) * (size_t)K + (tid & 3) * 8;
  char* lAb = (char*)&lA[0];
  char* lBb = (char*)&lB[0];

  for (int k0 = 0; k0 < K; k0 += 32) {
    __syncthreads();
#pragma unroll
    for (int s = 0; s < 2; ++s) {
      load_lds16(aSrc + (size_t)s * 64 * K + k0, lAb + s * 4096 + tid * 16);
      load_lds16(bSrc + (size_t)s * 64 * K + k0, lBb + s * 4096 + tid * 16);
    }
    __syncthreads();
    bf16x8 af[4], bfv[4];
#pragma unroll
    for (int i = 0; i < 4; ++i)
      af[i] = *(const bf16x8*)&lA[(wm + i * 16 + (lane & 15)) * 32 + (lane >> 4) * 8];
#pragma unroll
    for (int j = 0; j < 4; ++j)
      bfv[j] = *(const bf16x8*)&lB[(wn + j * 16 + (lane & 15)) * 32 + (lane >> 4) * 8];
#pragma unroll
    for (int i = 0; i < 4; ++i)
#pragma unroll
      for (int j = 0; j < 4; ++j)
        acc[i][j] = __builtin_amdgcn_mfma_f32_16x16x32_bf16(af[i], bfv[j], acc[i][j], 0, 0, 0);
  }
#pragma unroll
  for (int i = 0; i < 4; ++i)
#pragma unroll
    for (int j = 0; j < 4; ++j)
#pragma unroll
      for (int r = 0; r < 4; ++r) {
        const size_t row = row0 + wm + i * 16 + (lane >> 4) * 4 + r;
        const size_t col = col0 + wn + j * 16 + (lane & 15);
        C[row * (size_t)N + col] = acc[i][j][r] + bias[col];
      }
}

// ---------------------------------------------------------------------------
// Persistent LSTM scan with FENCE-FREE flag barrier.
// h stores: sc0 sc1 write-through to MALL (device-visible at vmcnt(0)).
// h reads: normal cached loads — each (b,t) slot is a distinct 2KB-aligned
// region never read before its flag posts, so reader L2 can't hold it stale;
// first read demand-misses to the MALL which has the written-through data.
// Flags: 128 per-layer words, one per block, written sc0 sc1 AFTER vmcnt(0)+
// __syncthreads; polled with sc0 sc1 loads (must bypass L2). No fences ->
// L2 (pre, Whh) stays warm; no wbl2/inv serialization.
// ---------------------------------------------------------------------------
__device__ __forceinline__ void wait_flags(const unsigned* flags, unsigned tgt) {
  const int lane = threadIdx.x & 63;
  const unsigned* p = flags + 2 * lane;      // 128 flags = 2 per lane
  int spins = 0;
  for (;;) {
    uint2 f = ld_coh_u32x2(p);
    if (__all(f.x >= tgt && f.y >= tgt)) break;
    if (++spins > 20000) break;              // ~5 ms escape: fail, don't hang
    __builtin_amdgcn_s_sleep(2);
  }
  asm volatile("" ::: "memory");             // no load hoisting above the poll
}

__global__ __launch_bounds__(256) void k_lstm_scan(
    bf16* __restrict__ hs, const float* __restrict__ pre,
    const bf16* __restrict__ whh, unsigned* __restrict__ flags)
{
  __shared__ bf16 lW[32 * 1024];               // 64 KB exactly
  const int tid  = threadIdx.x;
  const int lane = tid & 63;
  const int wave = tid >> 6;
  const int tn   = wave >> 1;                  // col-tile: cols 0-3 / 4-7
  const int tb   = wave & 1;                   // batch-tile: b 0-15 / 16-31
  const int n0   = blockIdx.x * 8;             // this block's hidden cols

  // ---- stage Whh slice: LDS row r <-> global row (r&3)*1024 + n0 + (r>>2)
#pragma unroll
  for (int it = 0; it < 16; ++it) {
    const int idx  = it * 256 + tid;           // 16B-chunk id, 0..4095
    const int r    = idx >> 7;                 // lds row 0..31
    const int c16  = idx & 127;                // 16B chunk within row
    const int grow = (r & 3) * 1024 + n0 + (r >> 2);
    const bf16x8 v = *(const bf16x8*)(whh + (size_t)grow * 1024 + c16 * 8);
    int byte = r * 2048 + c16 * 16;
    byte ^= (r & 7) << 4;                      // bank-conflict swizzle
    *(bf16x8*)((char*)lW + byte) = v;
  }
  __syncthreads();

  const int arow  = tn * 16 + (lane & 15);     // Whh LDS row for A-frag
  const int axor  = (arow & 7) << 4;
  const int abase = arow * 2048 + (lane >> 4) * 16;
  const int brow  = tb * 16 + (lane & 15);     // batch row (B-frag & owner)
  const int cown  = tn * 4 + (lane >> 4);      // owned col within block
  const char* lWb = (const char*)lW;

  float cstate = 0.f;
  const float* preb = pre + (size_t)brow * 64 * 4096 + (n0 + cown);
  bf16* hw = hs + (size_t)brow * 64 * 1024 + (n0 + cown);
  const bf16* hr = hs + (size_t)brow * 65536 + (lane >> 4) * 8;

#pragma unroll 1
  for (int t = 0; t < 64; ++t) {
    // pre loads issued before the poll (L2-warm, latency hidden under poll)
    const float* pp = preb + (size_t)t * 4096;
    float g0 = pp[0], g1 = pp[1024], g2 = pp[2048], g3 = pp[3072];
    if (t > 0) {
      wait_flags(flags, (unsigned)t);          // h_{t-1} globally visible
      const bf16* hp = hr + (size_t)(t - 1) * 1024;
      floatx4 acc0 = {}, acc1 = {};
#pragma unroll
      for (int kk = 0; kk < 32; kk += 2) {
        const bf16x8 a0 = *(const bf16x8*)(lWb + ((abase + kk * 64) ^ axor));
        const bf16x8 b0 = *(const bf16x8*)(hp + kk * 32);
        acc0 = __builtin_amdgcn_mfma_f32_16x16x32_bf16(a0, b0, acc0, 0, 0, 0);
        const bf16x8 a1 = *(const bf16x8*)(lWb + ((abase + kk * 64 + 64) ^ axor));
        const bf16x8 b1 = *(const bf16x8*)(hp + kk * 32 + 32);
        acc1 = __builtin_amdgcn_mfma_f32_16x16x32_bf16(a1, b1, acc1, 0, 0, 0);
      }
      g0 += acc0[0] + acc1[0];
      g1 += acc0[1] + acc1[1];
      g2 += acc0[2] + acc1[2];
      g3 += acc0[3] + acc1[3];
    }
    const float iv = sigm(g0), fv = sigm(g1), gv = tanh_f(g2), ov = sigm(g3);
    cstate = fv * cstate + iv * gv;
    const bf16 hval = (bf16)(ov * tanh_f(cstate));
    st_coh_u16(hw + (size_t)t * 1024,
               (unsigned)__builtin_bit_cast(unsigned short, hval));
    asm volatile("s_waitcnt vmcnt(0)" ::: "memory");   // h globally visible
    __syncthreads();                                   // whole block done
    if (tid == 0)
      st_coh_u32(flags + blockIdx.x, (unsigned)(t + 1));
  }
}

// ---------------------------------------------------------------------------
extern "C" void kernel_launch(void* const* d_in, const int* in_sizes, int n_in,
                              void* d_out, int out_size, void* d_ws, size_t ws_size,
                              hipStream_t stream)
{
  const float* image = (const float*)d_in[0];
  const int*   caps  = (const int*)d_in[1];
  const float* linW  = (const float*)d_in[2];
  const float* linb  = (const float*)d_in[3];
  const float* gamma = (const float*)d_in[4];
  const float* beta  = (const float*)d_in[5];
  const float* emb   = (const float*)d_in[6];
  const float* Wih0  = (const float*)d_in[7];
  const float* Whh0  = (const float*)d_in[8];
  const float* bih0  = (const float*)d_in[9];
  const float* bhh0  = (const float*)d_in[10];
  const float* Wih1  = (const float*)d_in[11];
  const float* Whh1  = (const float*)d_in[12];
  const float* bih1  = (const float*)d_in[13];
  const float* bhh1  = (const float*)d_in[14];
  const float* fcW   = (const float*)d_in[15];
  const float* fcb   = (const float*)d_in[16];
  float* out = (float*)d_out;

  char* ws = (char*)d_ws;
  size_t off = 0;
  auto alloc = [&](size_t bytes) {
    char* p = ws + off;
    off += (bytes + 255) & ~(size_t)255;
    return p;
  };
  // base footprint ~58 MB (proven); fcwb only if workspace allows
  bf16*  whh0b = (bf16*)alloc(4096ull * 1024 * 2);
  bf16*  whh1b = (bf16*)alloc(4096ull * 1024 * 2);
  bf16*  xsb   = (bf16*)alloc(2048ull * 512 * 2);
  bf16*  hs0b  = (bf16*)alloc(2048ull * 1024 * 2);
  bf16*  hs1b  = (bf16*)alloc(2048ull * 1024 * 2);
  float* pre   = (float*)alloc(2048ull * 4096 * 4);
  float* bsum0 = (float*)alloc(4096 * 4);
  float* bsum1 = (float*)alloc(4096 * 4);
  unsigned* flg = (unsigned*)alloc(1024);          // 2 layers x 128 flags
  const bool big = ws_size >= ((size_t)127 << 20); // need ~120.6 MiB for fcwb
  bf16* fcwb = big ? (bf16*)alloc(32000ull * 1024 * 2) : (bf16*)0;

  k_zero<<<1, 256, 0, stream>>>(flg);
  k_cvt<<<4096, 256, 0, stream>>>(Whh0, whh0b, 4096 * 1024 / 4);
  k_cvt<<<4096, 256, 0, stream>>>(Whh1, whh1b, 4096 * 1024 / 4);
  if (big) k_cvt<<<32000, 256, 0, stream>>>(fcW, fcwb, 32000 * 1024 / 4);
  k_bias_sum<<<16, 256, 0, stream>>>(bih0, bhh0, bsum0, 4096);
  k_bias_sum<<<16, 256, 0, stream>>>(bih1, bhh1, bsum1, 4096);
  k_linbn<<<512, 256, 0, stream>>>(image, linW, linb, gamma, beta, xsb);
  k_embed<<<2016, 128, 0, stream>>>(caps, emb, xsb);

  // layer 0
  k_gemm<<<dim3(16, 32), 256, 0, stream>>>(xsb, Wih0, bsum0, pre, 512, 4096);
  k_lstm_scan<<<128, 256, 0, stream>>>(hs0b, pre, whh0b, flg);
  // layer 1
  k_gemm<<<dim3(16, 32), 256, 0, stream>>>(hs0b, Wih1, bsum1, pre, 1024, 4096);
  k_lstm_scan<<<128, 256, 0, stream>>>(hs1b, pre, whh1b, flg + 128);
  // vocab projection
  if (big)
    k_gemm_bf<<<dim3(16, 250), 256, 0, stream>>>(hs1b, fcwb, fcb, out, 1024, 32000);
  else
    k_gemm<<<dim3(16, 250), 256, 0, stream>>>(hs1b, fcW, fcb, out, 1024, 32000);

  (void)in_sizes; (void)n_in; (void)out_size; (void)ws_size;
}

// Round 5
// 1476.366 us; speedup vs baseline: 1.2743x; 1.0034x over previous
//
#include <hip/hip_runtime.h>

typedef __bf16 bf16;
typedef __attribute__((ext_vector_type(4))) float floatx4;
typedef __attribute__((ext_vector_type(8))) bf16 bf16x8;
typedef __attribute__((ext_vector_type(4))) bf16 bf16x4;
typedef __attribute__((ext_vector_type(4))) unsigned uintx4;
typedef __attribute__((ext_vector_type(2))) unsigned uintx2;

typedef const __attribute__((address_space(1))) void gconst_t;
typedef __attribute__((address_space(3))) void lds_t;

__device__ __forceinline__ void load_lds16(const void* g, void* l) {
  __builtin_amdgcn_global_load_lds((gconst_t*)g, (lds_t*)l, 16, 0, 0);
}

__device__ __forceinline__ float sigm(float x) { return 1.f / (1.f + __expf(-x)); }
__device__ __forceinline__ float tanh_f(float x) { return 2.f / (1.f + __expf(-2.f * x)) - 1.f; }

// --- device-coherent (cross-XCD) access helpers: bypass L1/L2 via sc0 sc1 ---
__device__ __forceinline__ void st_coh_u32(void* p, unsigned v) {
  asm volatile("global_store_dword %0, %1, off sc0 sc1" :: "v"(p), "v"(v) : "memory");
}
__device__ __forceinline__ void st_coh_u128(void* p, uintx4 v) {
  asm volatile("global_store_dwordx4 %0, %1, off sc0 sc1" :: "v"(p), "v"(v) : "memory");
}
__device__ __forceinline__ uintx2 ld_coh_u32x2(const void* p) {
  uintx2 r;
  asm volatile("global_load_dwordx2 %0, %1, off sc0 sc1\n\ts_waitcnt vmcnt(0)"
               : "=v"(r) : "v"(p) : "memory");
  return r;
}

// ---------------------------------------------------------------------------
// fp32 -> bf16 convert (vectorized x4)
// ---------------------------------------------------------------------------
__global__ void k_cvt(const float* __restrict__ in, bf16* __restrict__ out, int n4) {
  int i = blockIdx.x * 256 + threadIdx.x;
  if (i < n4) {
    float4 v = ((const float4*)in)[i];
    bf16x4 u = { (bf16)v.x, (bf16)v.y, (bf16)v.z, (bf16)v.w };
    ((bf16x4*)out)[i] = u;
  }
}

__global__ void k_bias_sum(const float* __restrict__ a, const float* __restrict__ b,
                           float* __restrict__ o, int n) {
  int i = blockIdx.x * 256 + threadIdx.x;
  if (i < n) o[i] = a[i] + b[i];
}

__global__ void k_zero(unsigned* __restrict__ p) {
  p[threadIdx.x] = 0u;   // 256 flag words (two 128-block layers)
}

// ---------------------------------------------------------------------------
// linear (32x2048 @ 2048x512^T) + batchnorm over batch dim -> xs row t=0 (bf16)
// ---------------------------------------------------------------------------
__global__ __launch_bounds__(256) void k_linbn(
    const float* __restrict__ img, const float* __restrict__ W,
    const float* __restrict__ lb, const float* __restrict__ gamma,
    const float* __restrict__ beta, bf16* __restrict__ xs)
{
  const int e = blockIdx.x;                 // 0..511
  const int wave = threadIdx.x >> 6, lane = threadIdx.x & 63;
  __shared__ float sums[32];
  const float* wrow = W + (size_t)e * 2048;
  for (int b = wave; b < 32; b += 4) {
    const float* irow = img + (size_t)b * 2048;
    float s = 0.f;
#pragma unroll
    for (int j = 0; j < 8; ++j) {
      const int k = j * 256 + lane * 4;
      float4 a = *(const float4*)(irow + k);
      float4 w = *(const float4*)(wrow + k);
      s += a.x * w.x + a.y * w.y + a.z * w.z + a.w * w.w;
    }
#pragma unroll
    for (int off = 32; off > 0; off >>= 1) s += __shfl_down(s, off);
    if (lane == 0) sums[b] = s + lb[e];
  }
  __syncthreads();
  if (threadIdx.x < 32) {
    const float x = sums[threadIdx.x];
    float m = x, m2 = x * x;
#pragma unroll
    for (int mask = 16; mask > 0; mask >>= 1) {
      m  += __shfl_xor(m, mask);
      m2 += __shfl_xor(m2, mask);
    }
    m *= (1.f / 32.f); m2 *= (1.f / 32.f);
    const float var = m2 - m * m;
    const float xn = gamma[e] * (x - m) * rsqrtf(var + 1e-5f) + beta[e];
    xs[(size_t)threadIdx.x * 64 * 512 + e] = (bf16)xn;  // row r = b*64 + 0
  }
}

// ---------------------------------------------------------------------------
// embedding gather -> xs rows t=1..63 (bf16)
// ---------------------------------------------------------------------------
__global__ void k_embed(const int* __restrict__ cap, const float* __restrict__ emb,
                        bf16* __restrict__ xs)
{
  const int blk = blockIdx.x;               // 0..2015
  const int b = blk / 63, j = blk % 63;     // t = j+1
  const int tok = cap[b * 64 + j];
  const float* src = emb + (size_t)tok * 512;
  bf16* dst = xs + ((size_t)b * 64 + j + 1) * 512;
  float4 v = ((const float4*)src)[threadIdx.x];
  bf16x4 u = { (bf16)v.x, (bf16)v.y, (bf16)v.z, (bf16)v.w };
  *(bf16x4*)(dst + threadIdx.x * 4) = u;
}

// ---------------------------------------------------------------------------
// GEMM: C[M,N] = A[M,K](bf16) @ Bt[N,K](fp32, cvt during staging)^T + bias.
// m97 structure + XCD-chunked swizzle. (fallback / small-GEMM path)
// ---------------------------------------------------------------------------
__global__ __launch_bounds__(256) void k_gemm(
    const bf16* __restrict__ A, const float* __restrict__ Bt,
    const float* __restrict__ bias, float* __restrict__ C,
    int K, int N)
{
  __shared__ bf16 lA[128 * 32];
  __shared__ bf16 lB[128 * 32];
  const int tid = threadIdx.x;
  const int lane = tid & 63;
  const int wm = ((tid >> 6) >> 1) * 64;
  const int wn = ((tid >> 6) & 1) * 64;
  const int nwg = gridDim.x * gridDim.y;
  int wg = blockIdx.y * gridDim.x + blockIdx.x;
  wg = (wg & 7) * (nwg >> 3) + (wg >> 3);        // XCD-chunked, bijective (nwg%8==0)
  const size_t row0 = (size_t)(wg & 15) * 128;   // gridDim.x == 16 always
  const size_t col0 = (size_t)(wg >> 4) * 128;
  floatx4 acc[4][4] = {};
  const bf16*  aSrc = A  + (row0 + (tid >> 2)) * (size_t)K + (tid & 3) * 8;
  const float* bSrc = Bt + (col0 + (tid >> 3)) * (size_t)K + (tid & 7) * 4;
  char* lAb = (char*)&lA[0];

  for (int k0 = 0; k0 < K; k0 += 32) {
    __syncthreads();
#pragma unroll
    for (int s = 0; s < 2; ++s)   // A tile: 128x32 bf16 via lds-DMA, 2 shots
      load_lds16(aSrc + (size_t)s * 64 * K + k0, lAb + s * 4096 + tid * 16);
#pragma unroll
    for (int s = 0; s < 4; ++s) { // B tile: 128x32 fp32 -> bf16, 4 shots
      float4 v = *(const float4*)(bSrc + (size_t)s * 32 * K + k0);
      bf16x4 u = { (bf16)v.x, (bf16)v.y, (bf16)v.z, (bf16)v.w };
      *(bf16x4*)&lB[(s * 32 + (tid >> 3)) * 32 + (tid & 7) * 4] = u;
    }
    __syncthreads();
    bf16x8 af[4], bfv[4];
#pragma unroll
    for (int i = 0; i < 4; ++i)
      af[i] = *(const bf16x8*)&lA[(wm + i * 16 + (lane & 15)) * 32 + (lane >> 4) * 8];
#pragma unroll
    for (int j = 0; j < 4; ++j)
      bfv[j] = *(const bf16x8*)&lB[(wn + j * 16 + (lane & 15)) * 32 + (lane >> 4) * 8];
#pragma unroll
    for (int i = 0; i < 4; ++i)
#pragma unroll
      for (int j = 0; j < 4; ++j)
        acc[i][j] = __builtin_amdgcn_mfma_f32_16x16x32_bf16(af[i], bfv[j], acc[i][j], 0, 0, 0);
  }
#pragma unroll
  for (int i = 0; i < 4; ++i)
#pragma unroll
    for (int j = 0; j < 4; ++j)
#pragma unroll
      for (int r = 0; r < 4; ++r) {
        const size_t row = row0 + wm + i * 16 + (lane >> 4) * 4 + r;
        const size_t col = col0 + wn + j * 16 + (lane & 15);
        C[row * (size_t)N + col] = acc[i][j][r] + bias[col];
      }
}

// ---------------------------------------------------------------------------
// GEMM variant: B already bf16 -> both operands via lds-DMA (m97 fast path).
// ---------------------------------------------------------------------------
__global__ __launch_bounds__(256) void k_gemm_bf(
    const bf16* __restrict__ A, const bf16* __restrict__ B,
    const float* __restrict__ bias, float* __restrict__ C,
    int K, int N)
{
  __shared__ bf16 lA[128 * 32];
  __shared__ bf16 lB[128 * 32];
  const int tid = threadIdx.x;
  const int lane = tid & 63;
  const int wm = ((tid >> 6) >> 1) * 64;
  const int wn = ((tid >> 6) & 1) * 64;
  const int nwg = gridDim.x * gridDim.y;
  int wg = blockIdx.y * gridDim.x + blockIdx.x;
  wg = (wg & 7) * (nwg >> 3) + (wg >> 3);
  const size_t row0 = (size_t)(wg & 15) * 128;
  const size_t col0 = (size_t)(wg >> 4) * 128;
  floatx4 acc[4][4] = {};
  const bf16* aSrc = A + (row0 + (tid >> 2)) * (size_t)K + (tid & 3) * 8;
  const bf16* bSrc = B + (col0 + (tid >> 2)) * (size_t)K + (tid & 3) * 8;
  char* lAb = (char*)&lA[0];
  char* lBb = (char*)&lB[0];

  for (int k0 = 0; k0 < K; k0 += 32) {
    __syncthreads();
#pragma unroll
    for (int s = 0; s < 2; ++s) {
      load_lds16(aSrc + (size_t)s * 64 * K + k0, lAb + s * 4096 + tid * 16);
      load_lds16(bSrc + (size_t)s * 64 * K + k0, lBb + s * 4096 + tid * 16);
    }
    __syncthreads();
    bf16x8 af[4], bfv[4];
#pragma unroll
    for (int i = 0; i < 4; ++i)
      af[i] = *(const bf16x8*)&lA[(wm + i * 16 + (lane & 15)) * 32 + (lane >> 4) * 8];
#pragma unroll
    for (int j = 0; j < 4; ++j)
      bfv[j] = *(const bf16x8*)&lB[(wn + j * 16 + (lane & 15)) * 32 + (lane >> 4) * 8];
#pragma unroll
    for (int i = 0; i < 4; ++i)
#pragma unroll
      for (int j = 0; j < 4; ++j)
        acc[i][j] = __builtin_amdgcn_mfma_f32_16x16x32_bf16(af[i], bfv[j], acc[i][j], 0, 0, 0);
  }
#pragma unroll
  for (int i = 0; i < 4; ++i)
#pragma unroll
    for (int j = 0; j < 4; ++j)
#pragma unroll
      for (int r = 0; r < 4; ++r) {
        const size_t row = row0 + wm + i * 16 + (lane >> 4) * 4 + r;
        const size_t col = col0 + wn + j * 16 + (lane & 15);
        C[row * (size_t)N + col] = acc[i][j][r] + bias[col];
      }
}

// ---------------------------------------------------------------------------
// Persistent LSTM scan, fence-free flag barrier, low-contention variant:
//  - only wave 0 polls the 128 flags (sc0 sc1); waves 1-3 wait at a barrier.
//    4x fewer MALL poll requests -> lower contended round-trip latency.
//  - h stores coalesced: each block's 32x8 bf16 slice staged in LDS, then 32
//    lanes store 16B dwordx4 sc0 sc1 (4k instead of 32k transactions/step).
// Protocol unchanged from the verified r3 kernel: slot (b,t) written once,
// flags posted only after the block's stores drained (vmcnt 0 + barrier).
// ---------------------------------------------------------------------------
__device__ __forceinline__ void wait_flags(const unsigned* flags, unsigned tgt) {
  const int lane = threadIdx.x & 63;
  const unsigned* p = flags + 2 * lane;      // 128 flags = 2 per lane
  int spins = 0;
  for (;;) {
    uintx2 f = ld_coh_u32x2(p);
    if (__all(f.x >= tgt && f.y >= tgt)) break;
    if (++spins > 50000) break;              // escape: fail, don't hang
    __builtin_amdgcn_s_sleep(1);
  }
  asm volatile("" ::: "memory");             // no load hoisting above the poll
}

__global__ __launch_bounds__(256) void k_lstm_scan(
    bf16* __restrict__ hs, const float* __restrict__ pre,
    const bf16* __restrict__ whh, unsigned* __restrict__ flags)
{
  __shared__ bf16 lW[32 * 1024];               // 64 KB
  __shared__ bf16 hstage[32][8];               // h slice gather (512 B)
  const int tid  = threadIdx.x;
  const int lane = tid & 63;
  const int wave = tid >> 6;
  const int tn   = wave >> 1;                  // col-tile: cols 0-3 / 4-7
  const int tb   = wave & 1;                   // batch-tile: b 0-15 / 16-31
  const int n0   = blockIdx.x * 8;             // this block's hidden cols

  // ---- stage Whh slice: LDS row r <-> global row (r&3)*1024 + n0 + (r>>2)
#pragma unroll
  for (int it = 0; it < 16; ++it) {
    const int idx  = it * 256 + tid;           // 16B-chunk id, 0..4095
    const int r    = idx >> 7;                 // lds row 0..31
    const int c16  = idx & 127;                // 16B chunk within row
    const int grow = (r & 3) * 1024 + n0 + (r >> 2);
    const bf16x8 v = *(const bf16x8*)(whh + (size_t)grow * 1024 + c16 * 8);
    int byte = r * 2048 + c16 * 16;
    byte ^= (r & 7) << 4;                      // bank-conflict swizzle
    *(bf16x8*)((char*)lW + byte) = v;
  }
  __syncthreads();

  const int arow  = tn * 16 + (lane & 15);     // Whh LDS row for A-frag
  const int axor  = (arow & 7) << 4;
  const int abase = arow * 2048 + (lane >> 4) * 16;
  const int brow  = tb * 16 + (lane & 15);     // batch row (B-frag & owner)
  const int cown  = tn * 4 + (lane >> 4);      // owned col within block
  const char* lWb = (const char*)lW;

  float cstate = 0.f;
  const float* preb = pre + (size_t)brow * 64 * 4096 + (n0 + cown);
  const bf16* hr = hs + (size_t)brow * 65536 + (lane >> 4) * 8;
  bf16* hwrow = hs + (size_t)tid * 65536 + n0; // tid<32: batch row store base

#pragma unroll 1
  for (int t = 0; t < 64; ++t) {
    // pre loads issued before the poll (latency hidden under poll/barrier)
    const float* pp = preb + (size_t)t * 4096;
    float g0 = pp[0], g1 = pp[1024], g2 = pp[2048], g3 = pp[3072];
    if (t > 0) {
      if (wave == 0) wait_flags(flags, (unsigned)t);
      __syncthreads();                         // release waves 1-3 post-detect
      const bf16* hp = hr + (size_t)(t - 1) * 1024;
      floatx4 acc0 = {}, acc1 = {};
#pragma unroll
      for (int kk = 0; kk < 32; kk += 2) {
        const bf16x8 a0 = *(const bf16x8*)(lWb + ((abase + kk * 64) ^ axor));
        const bf16x8 b0 = *(const bf16x8*)(hp + kk * 32);
        acc0 = __builtin_amdgcn_mfma_f32_16x16x32_bf16(a0, b0, acc0, 0, 0, 0);
        const bf16x8 a1 = *(const bf16x8*)(lWb + ((abase + kk * 64 + 64) ^ axor));
        const bf16x8 b1 = *(const bf16x8*)(hp + kk * 32 + 32);
        acc1 = __builtin_amdgcn_mfma_f32_16x16x32_bf16(a1, b1, acc1, 0, 0, 0);
      }
      g0 += acc0[0] + acc1[0];
      g1 += acc0[1] + acc1[1];
      g2 += acc0[2] + acc1[2];
      g3 += acc0[3] + acc1[3];
    }
    const float iv = sigm(g0), fv = sigm(g1), gv = tanh_f(g2), ov = sigm(g3);
    cstate = fv * cstate + iv * gv;
    hstage[brow][cown] = (bf16)(ov * tanh_f(cstate));
    __syncthreads();                           // hstage complete
    if (tid < 32) {                            // 1 lane per batch row: 16B store
      const uintx4 hv = *(const uintx4*)&hstage[tid][0];
      st_coh_u128(hwrow + (size_t)t * 1024, hv);
      asm volatile("s_waitcnt vmcnt(0)" ::: "memory");
    }
    __syncthreads();                           // all h stores drained
    if (tid == 0)
      st_coh_u32(flags + blockIdx.x, (unsigned)(t + 1));
  }
}

// ---------------------------------------------------------------------------
extern "C" void kernel_launch(void* const* d_in, const int* in_sizes, int n_in,
                              void* d_out, int out_size, void* d_ws, size_t ws_size,
                              hipStream_t stream)
{
  const float* image = (const float*)d_in[0];
  const int*   caps  = (const int*)d_in[1];
  const float* linW  = (const float*)d_in[2];
  const float* linb  = (const float*)d_in[3];
  const float* gamma = (const float*)d_in[4];
  const float* beta  = (const float*)d_in[5];
  const float* emb   = (const float*)d_in[6];
  const float* Wih0  = (const float*)d_in[7];
  const float* Whh0  = (const float*)d_in[8];
  const float* bih0  = (const float*)d_in[9];
  const float* bhh0  = (const float*)d_in[10];
  const float* Wih1  = (const float*)d_in[11];
  const float* Whh1  = (const float*)d_in[12];
  const float* bih1  = (const float*)d_in[13];
  const float* bhh1  = (const float*)d_in[14];
  const float* fcW   = (const float*)d_in[15];
  const float* fcb   = (const float*)d_in[16];
  float* out = (float*)d_out;

  char* ws = (char*)d_ws;
  size_t off = 0;
  auto alloc = [&](size_t bytes) {
    char* p = ws + off;
    off += (bytes + 255) & ~(size_t)255;
    return p;
  };
  // base footprint ~58 MB (proven); fcwb only if workspace allows
  bf16*  whh0b = (bf16*)alloc(4096ull * 1024 * 2);
  bf16*  whh1b = (bf16*)alloc(4096ull * 1024 * 2);
  bf16*  xsb   = (bf16*)alloc(2048ull * 512 * 2);
  bf16*  hs0b  = (bf16*)alloc(2048ull * 1024 * 2);
  bf16*  hs1b  = (bf16*)alloc(2048ull * 1024 * 2);
  float* pre   = (float*)alloc(2048ull * 4096 * 4);
  float* bsum0 = (float*)alloc(4096 * 4);
  float* bsum1 = (float*)alloc(4096 * 4);
  unsigned* flg = (unsigned*)alloc(1024);          // 2 layers x 128 flags
  const bool big = ws_size >= ((size_t)127 << 20); // need ~120.6 MiB for fcwb
  bf16* fcwb = big ? (bf16*)alloc(32000ull * 1024 * 2) : (bf16*)0;

  k_zero<<<1, 256, 0, stream>>>(flg);
  k_cvt<<<4096, 256, 0, stream>>>(Whh0, whh0b, 4096 * 1024 / 4);
  k_cvt<<<4096, 256, 0, stream>>>(Whh1, whh1b, 4096 * 1024 / 4);
  if (big) k_cvt<<<32000, 256, 0, stream>>>(fcW, fcwb, 32000 * 1024 / 4);
  k_bias_sum<<<16, 256, 0, stream>>>(bih0, bhh0, bsum0, 4096);
  k_bias_sum<<<16, 256, 0, stream>>>(bih1, bhh1, bsum1, 4096);
  k_linbn<<<512, 256, 0, stream>>>(image, linW, linb, gamma, beta, xsb);
  k_embed<<<2016, 128, 0, stream>>>(caps, emb, xsb);

  // layer 0
  k_gemm<<<dim3(16, 32), 256, 0, stream>>>(xsb, Wih0, bsum0, pre, 512, 4096);
  k_lstm_scan<<<128, 256, 0, stream>>>(hs0b, pre, whh0b, flg);
  // layer 1
  k_gemm<<<dim3(16, 32), 256, 0, stream>>>(hs0b, Wih1, bsum1, pre, 1024, 4096);
  k_lstm_scan<<<128, 256, 0, stream>>>(hs1b, pre, whh1b, flg + 128);
  // vocab projection
  if (big)
    k_gemm_bf<<<dim3(16, 250), 256, 0, stream>>>(hs1b, fcwb, fcb, out, 1024, 32000);
  else
    k_gemm<<<dim3(16, 250), 256, 0, stream>>>(hs1b, fcW, fcb, out, 1024, 32000);

  (void)in_sizes; (void)n_in; (void)out_size; (void)ws_size;
}